// Round 5
// baseline (570.578 us; speedup 1.0000x reference)
//
#include <hip/hip_runtime.h>
#include <math.h>

#define SCALE_ 0.125f

typedef _Float16 half_t;
typedef __attribute__((ext_vector_type(8))) _Float16 f16x8;
typedef __attribute__((ext_vector_type(4))) _Float16 f16x4;
typedef __attribute__((ext_vector_type(4))) float f32x4;

#define AS1 __attribute__((address_space(1)))
#define AS3 __attribute__((address_space(3)))

__device__ __forceinline__ f32x4 mfma16(f16x8 a, f16x8 b, f32x4 c) {
  return __builtin_amdgcn_mfma_f32_16x16x32_f16(a, b, c, 0, 0, 0);
}
__device__ __forceinline__ void gload16(const void* g, void* l) {
  __builtin_amdgcn_global_load_lds((const AS1 void*)g, (AS3 void*)l, 16, 0, 0);
}
// split f into fp16 hi + fp16 lo (residual); hi+lo ~ 2^-22 relative accuracy
__device__ __forceinline__ void split2(float f, half_t* h, half_t* l) {
  half_t hh = (half_t)f;
  *h = hh;
  *l = (half_t)(f - (float)hh);
}

// ---------------------------------------------------------------------------
// Convert+transpose 6 weight mats: fp32 [K=1024][N=1024] -> fp16 hi/lo [N][K]
// ---------------------------------------------------------------------------
__global__ __launch_bounds__(256) void convw_kernel(
    const float* __restrict__ W0, const float* __restrict__ W1,
    const float* __restrict__ W2, const float* __restrict__ W3,
    const float* __restrict__ W4, const float* __restrict__ W5,
    half_t* __restrict__ wh, half_t* __restrict__ wl)
{
  const int z = blockIdx.z;
  const float* W = (z == 0) ? W0 : (z == 1) ? W1 : (z == 2) ? W2
                  : (z == 3) ? W3 : (z == 4) ? W4 : W5;
  half_t* outh = wh + z * 1048576;
  half_t* outl = wl + z * 1048576;
  const int n0 = blockIdx.x * 32, k0 = blockIdx.y * 32;
  const int t = threadIdx.x, r = t >> 3, c4 = (t & 7) * 4;
  __shared__ float lds[32][33];
  float4 v = *(const float4*)&W[(k0 + r) * 1024 + n0 + c4];
  lds[r][c4 + 0] = v.x; lds[r][c4 + 1] = v.y;
  lds[r][c4 + 2] = v.z; lds[r][c4 + 3] = v.w;
  __syncthreads();
  f16x4 oh, ol;
#pragma unroll
  for (int j = 0; j < 4; ++j) {
    const float f = lds[c4 + j][r];
    half_t hv, lv; split2(f, &hv, &lv);
    oh[j] = hv; ol[j] = lv;
  }
  *(f16x4*)&outh[(n0 + r) * 1024 + k0 + c4] = oh;
  *(f16x4*)&outl[(n0 + r) * 1024 + k0 + c4] = ol;
}

// ---------------------------------------------------------------------------
// x fp32 [4096][1024] -> fp16 hi/lo (same layout)
// ---------------------------------------------------------------------------
__global__ __launch_bounds__(256) void convx_kernel(
    const float* __restrict__ x, half_t* __restrict__ xh, half_t* __restrict__ xl)
{
  const int i = (blockIdx.x * 256 + threadIdx.x) * 4;
  float4 v = *(const float4*)&x[i];
  float vv[4] = {v.x, v.y, v.z, v.w};
  f16x4 oh, ol;
#pragma unroll
  for (int j = 0; j < 4; ++j) {
    half_t hv, lv; split2(vv[j], &hv, &lv);
    oh[j] = hv; ol[j] = lv;
  }
  *(f16x4*)&xh[i] = oh;
  *(f16x4*)&xl[i] = ol;
}

// ---------------------------------------------------------------------------
// Split-fp16 MFMA GEMM, m97 structure: 128x128 tile, BK=32, 4 waves (2x2),
// global_load_lds w=16, 3-term (AhBh + AhBl + AlBh).
// proj mode z: 0=Wq_re 1=Wq_im 2=Wk_re 3=Wk_im (fp16-split into qt/kt at
// remapped cols [h*128 + d (+64 for im)]), 4=Wv (written transposed split).
// final_mode: A=abuf, B=Wo (widx 5), out fp32.
// ---------------------------------------------------------------------------
__global__ __launch_bounds__(256) void gemm_kernel(
    const half_t* __restrict__ Agh, const half_t* __restrict__ Agl,
    const half_t* __restrict__ wh, const half_t* __restrict__ wl,
    half_t* __restrict__ qth, half_t* __restrict__ qtl,
    half_t* __restrict__ kth, half_t* __restrict__ ktl,
    half_t* __restrict__ vTh, half_t* __restrict__ vTl,
    float* __restrict__ outp, int final_mode)
{
  __shared__ half_t Ash[4096], Asl[4096], Bsh[4096], Bsl[4096];  // 4x8KB
  const int z = blockIdx.z;
  const int widx = final_mode ? 5 : z;
  const half_t* Bth = wh + widx * 1048576;
  const half_t* Btl = wl + widx * 1048576;

  const int n0 = blockIdx.x * 128, m0 = blockIdx.y * 128;
  const int tid = threadIdx.x, lane = tid & 63, wid = tid >> 6;
  const int wr = wid >> 1, wc = wid & 1, l15 = lane & 15, l4 = lane >> 4;

  f32x4 acc[4][4];
#pragma unroll
  for (int i = 0; i < 4; ++i)
#pragma unroll
    for (int j = 0; j < 4; ++j) acc[i][j] = (f32x4){0.f, 0.f, 0.f, 0.f};

  // staging: tile = 512 16B-slots; slot s -> row s>>2, halfcol (s&3)*8
  const int s0 = wid * 64 + lane, s1 = s0 + 256;
  const int r0 = s0 >> 2, c0 = (s0 & 3) * 8;
  const int r1 = s1 >> 2, c1 = (s1 & 3) * 8;
  half_t* Ah0 = Ash + wid * 512;        half_t* Ah1 = Ash + 2048 + wid * 512;
  half_t* Al0 = Asl + wid * 512;        half_t* Al1 = Asl + 2048 + wid * 512;
  half_t* Bh0 = Bsh + wid * 512;        half_t* Bh1 = Bsh + 2048 + wid * 512;
  half_t* Bl0 = Bsl + wid * 512;        half_t* Bl1 = Bsl + 2048 + wid * 512;

  for (int k0 = 0; k0 < 1024; k0 += 32) {
    __syncthreads();
    gload16(Agh + (m0 + r0) * 1024 + k0 + c0, Ah0);
    gload16(Agh + (m0 + r1) * 1024 + k0 + c1, Ah1);
    gload16(Agl + (m0 + r0) * 1024 + k0 + c0, Al0);
    gload16(Agl + (m0 + r1) * 1024 + k0 + c1, Al1);
    gload16(Bth + (n0 + r0) * 1024 + k0 + c0, Bh0);
    gload16(Bth + (n0 + r1) * 1024 + k0 + c1, Bh1);
    gload16(Btl + (n0 + r0) * 1024 + k0 + c0, Bl0);
    gload16(Btl + (n0 + r1) * 1024 + k0 + c1, Bl1);
    __syncthreads();
    f16x8 ah[4], al[4], bh[4], bl[4];
#pragma unroll
    for (int i = 0; i < 4; ++i) {
      const int ro = (wr * 64 + i * 16 + l15) * 32 + l4 * 8;
      ah[i] = *(const f16x8*)&Ash[ro];
      al[i] = *(const f16x8*)&Asl[ro];
    }
#pragma unroll
    for (int j = 0; j < 4; ++j) {
      const int ro = (wc * 64 + j * 16 + l15) * 32 + l4 * 8;
      bh[j] = *(const f16x8*)&Bsh[ro];
      bl[j] = *(const f16x8*)&Bsl[ro];
    }
#pragma unroll
    for (int i = 0; i < 4; ++i)
#pragma unroll
      for (int j = 0; j < 4; ++j) {
        acc[i][j] = mfma16(ah[i], bh[j], acc[i][j]);
        acc[i][j] = mfma16(ah[i], bl[j], acc[i][j]);
        acc[i][j] = mfma16(al[i], bh[j], acc[i][j]);
      }
  }

#pragma unroll
  for (int i = 0; i < 4; ++i) {
    const int mb = m0 + wr * 64 + i * 16 + l4 * 4;
#pragma unroll
    for (int j = 0; j < 4; ++j) {
      const int n = n0 + wc * 64 + j * 16 + l15;
      if (final_mode) {
#pragma unroll
        for (int r = 0; r < 4; ++r) outp[(mb + r) * 1024 + n] = acc[i][j][r];
      } else if (z < 4) {
        half_t* dh = (z < 2) ? qth : kth;
        half_t* dl = (z < 2) ? qtl : ktl;
        const int colr = (n >> 6) * 128 + (n & 63) + ((z & 1) ? 64 : 0);
#pragma unroll
        for (int r = 0; r < 4; ++r) {
          half_t hv, lv; split2(acc[i][j][r], &hv, &lv);
          dh[(mb + r) * 2048 + colr] = hv;
          dl[(mb + r) * 2048 + colr] = lv;
        }
      } else {  // V: write transposed split, [bh][d][t], r -> contiguous t
        const int hh = n >> 6, d = n & 63;
        const int bq = mb >> 11, t = mb & 2047;
        f16x4 vh4, vl4;
#pragma unroll
        for (int r = 0; r < 4; ++r) {
          half_t hv, lv; split2(acc[i][j][r], &hv, &lv);
          vh4[r] = hv; vl4[r] = lv;
        }
        const int off = ((bq * 16 + hh) * 64 + d) * 2048 + t;
        *(f16x4*)&vTh[off] = vh4;
        *(f16x4*)&vTl[off] = vl4;
      }
    }
  }
}

// ---------------------------------------------------------------------------
// RoPE: reconstruct fp32 from hi+lo, rotate, re-split to qb/kb [bh][t][128]
// (re|im), q pre-scaled by SCALE. One 64-lane wave per (m,h).
// ---------------------------------------------------------------------------
__global__ __launch_bounds__(256) void rope_kernel(
    const half_t* __restrict__ qth, const half_t* __restrict__ qtl,
    const half_t* __restrict__ kth, const half_t* __restrict__ ktl,
    const float* __restrict__ cosb, const float* __restrict__ sinb,
    half_t* __restrict__ qbh, half_t* __restrict__ qbl,
    half_t* __restrict__ kbh, half_t* __restrict__ kbl)
{
  const int z = blockIdx.y;
  const int g = blockIdx.x * 4 + (threadIdx.x >> 6);
  const int d = threadIdx.x & 63;
  const int m = g >> 4, h = g & 15;
  const int b = m >> 11, t = m & 2047;
  const half_t* sh = (z ? kth : qth) + m * 2048 + h * 128;
  const half_t* sl = (z ? ktl : qtl) + m * 2048 + h * 128;
  const float re = (float)sh[d] + (float)sl[d];
  const float im = (float)sh[64 + d] + (float)sl[64 + d];
  const float c = cosb[t * 64 + d], s = sinb[t * 64 + d];
  float rer = re * c - im * s;
  float imr = re * s + im * c;
  if (z == 0) { rer *= SCALE_; imr *= SCALE_; }
  half_t* dh = (z ? kbh : qbh) + ((b * 16 + h) * 2048 + t) * 128;
  half_t* dl = (z ? kbl : qbl) + ((b * 16 + h) * 2048 + t) * 128;
  half_t hv, lv;
  split2(rer, &hv, &lv); dh[d] = hv;      dl[d] = lv;
  split2(imr, &hv, &lv); dh[64 + d] = hv; dl[64 + d] = lv;
}

// ---------------------------------------------------------------------------
// Flash attention, split-fp16 MFMA. 512 thr (8 waves); wave w owns q-rows
// q0+w*16..+15. QB=128, KB=32, D'=128, Dv=64.
// Single barrier per k-tile: double-buffered K/V staged via global_load_lds
// with pre-swizzled global source (linear LDS dest); prefetch of tile t+1
// issued right after the barrier, landing during tile t's compute.
// P LDS is wave-private (no barrier needed around it).
// ---------------------------------------------------------------------------
__global__ __launch_bounds__(512) void attn_kernel(
    const half_t* __restrict__ qbh, const half_t* __restrict__ qbl,
    const half_t* __restrict__ kbh, const half_t* __restrict__ kbl,
    const half_t* __restrict__ vTh, const half_t* __restrict__ vTl,
    half_t* __restrict__ abh, half_t* __restrict__ abl)
{
  const int qt = (int)gridDim.x - 1 - (int)blockIdx.x;  // big tiles first
  const int bh = blockIdx.y;
  const int b = bh >> 4, h = bh & 15;
  const int tid = threadIdx.x, lane = tid & 63, w = tid >> 6;
  const int l15 = lane & 15, l4 = lane >> 4;
  const int q0 = qt * 128;

  __shared__ half_t Kh[2][4096], Kl[2][4096];  // [32 t][128 d] per buf (16KB+16KB)
  __shared__ half_t Vh[2][2048], Vl[2][2048];  // [64 d][32 t] per buf (8KB+8KB)
  __shared__ half_t Ph[4096], Pl[4096];        // [128 q][32 k]       (8KB+8KB)

  // Q fragments (hi/lo), rows q0 + w*16 + l15
  f16x8 qh[4], ql[4];
  {
    const int qoff = (bh * 2048 + q0 + w * 16 + l15) * 128;
#pragma unroll
    for (int c = 0; c < 4; ++c) {
      qh[c] = *(const f16x8*)(qbh + qoff + c * 32 + l4 * 8);
      ql[c] = *(const f16x8*)(qbl + qoff + c * 32 + l4 * 8);
    }
  }

  f32x4 o[4];
#pragma unroll
  for (int n = 0; n < 4; ++n) o[n] = (f32x4){0.f, 0.f, 0.f, 0.f};
  float mrow[4] = {-3e38f, -3e38f, -3e38f, -3e38f};
  float lrow[4] = {0.f, 0.f, 0.f, 0.f};

  const half_t* kh_p = kbh + (size_t)bh * 2048 * 128;
  const half_t* kl_p = kbl + (size_t)bh * 2048 * 128;
  const half_t* vh_p = vTh + (size_t)bh * 64 * 2048;
  const half_t* vl_p = vTl + (size_t)bh * 64 * 2048;

  // staging geometry: K tile = 512 16B-slots (wave w -> slots w*64+lane);
  // lane's LDS slot is linear (gload_lds scatters lane*16B); the global
  // source is pre-swizzled so that swizzled READS see the right data.
  const int krow = w * 4 + (lane >> 4);            // 0..31
  const int ks = lane & 15;
  const int kg = (ks & 8) | ((ks & 7) ^ (krow & 7));  // involution
  const int vrow = (w & 3) * 16 + (lane >> 2);     // 0..63
  const int vs = lane & 3;
  const int vg = vs ^ ((vrow >> 1) & 3);           // involution
  const bool vhi = (w < 4);

  const int nkt = 4 * (qt + 1);
  const int qminw = q0 + w * 16, qmaxw = qminw + 15;

  // prologue: stage tile 0 into buf 0
  gload16(kh_p + (krow) * 128 + kg * 8, &Kh[0][w * 512]);
  gload16(kl_p + (krow) * 128 + kg * 8, &Kl[0][w * 512]);
  if (vhi) gload16(vh_p + vrow * 2048 + vg * 8, &Vh[0][(w & 3) * 512]);
  else     gload16(vl_p + vrow * 2048 + vg * 8, &Vl[0][(w & 3) * 512]);

  for (int kt = 0; kt < nkt; ++kt) {
    const int k0 = kt * 32;
    const int cb = kt & 1;
    __syncthreads();  // drains tile-kt loads; all waves done reading buf cb^1

    // prefetch tile kt+1 (clamped) into the other buffer; lands during compute
    {
      const int k0n = (kt + 1 < nkt) ? k0 + 32 : 0;
      const int nb = cb ^ 1;
      gload16(kh_p + (k0n + krow) * 128 + kg * 8, &Kh[nb][w * 512]);
      gload16(kl_p + (k0n + krow) * 128 + kg * 8, &Kl[nb][w * 512]);
      if (vhi) gload16(vh_p + vrow * 2048 + k0n + vg * 8, &Vh[nb][(w & 3) * 512]);
      else     gload16(vl_p + vrow * 2048 + k0n + vg * 8, &Vl[nb][(w & 3) * 512]);
    }

    if (k0 > qmaxw) continue;  // fully masked for this wave (barrier stays aligned)

    // S = Q K^T (k-cols k0 + n*16+l15, n=0..1), 3-term split
    f32x4 s[2];
    s[0] = (f32x4){0.f, 0.f, 0.f, 0.f};
    s[1] = (f32x4){0.f, 0.f, 0.f, 0.f};
#pragma unroll
    for (int c = 0; c < 4; ++c) {
#pragma unroll
      for (int n = 0; n < 2; ++n) {
        const int row = n * 16 + l15;
        const int co = c * 4 + l4;
        const int sr = (co & 8) | ((co & 7) ^ (row & 7));
        const f16x8 kfh = *(const f16x8*)&Kh[cb][row * 128 + sr * 8];
        const f16x8 kfl = *(const f16x8*)&Kl[cb][row * 128 + sr * 8];
        s[n] = mfma16(qh[c], kfh, s[n]);
        s[n] = mfma16(qh[c], kfl, s[n]);
        s[n] = mfma16(ql[c], kfh, s[n]);
      }
    }

    if (k0 + 31 > qminw) {  // partial tile: elementwise causal mask (global idx)
#pragma unroll
      for (int n = 0; n < 2; ++n)
#pragma unroll
        for (int r = 0; r < 4; ++r)
          if (k0 + n * 16 + l15 > qminw + l4 * 4 + r) s[n][r] = -3e38f;
    }

    // online softmax (row groups = 16 contiguous lanes)
#pragma unroll
    for (int r = 0; r < 4; ++r) {
      float mx = fmaxf(s[0][r], s[1][r]);
      mx = fmaxf(mx, __shfl_xor(mx, 1));
      mx = fmaxf(mx, __shfl_xor(mx, 2));
      mx = fmaxf(mx, __shfl_xor(mx, 4));
      mx = fmaxf(mx, __shfl_xor(mx, 8));
      const float mnew = fmaxf(mrow[r], mx);
      const float alpha = __expf(mrow[r] - mnew);
      const float p0 = __expf(s[0][r] - mnew);
      const float p1 = __expf(s[1][r] - mnew);
      float rs = p0 + p1;
      rs += __shfl_xor(rs, 1);
      rs += __shfl_xor(rs, 2);
      rs += __shfl_xor(rs, 4);
      rs += __shfl_xor(rs, 8);
      lrow[r] = lrow[r] * alpha + rs;
      mrow[r] = mnew;
#pragma unroll
      for (int n = 0; n < 4; ++n) o[n][r] *= alpha;
      const int prow = w * 16 + l4 * 4 + r;
      const int psw = (prow >> 2) & 3;
      half_t hv, lv;
      split2(p0, &hv, &lv);
      {
        const int col = l15, sp = (col >> 3) ^ psw;
        Ph[prow * 32 + sp * 8 + (col & 7)] = hv;
        Pl[prow * 32 + sp * 8 + (col & 7)] = lv;
      }
      split2(p1, &hv, &lv);
      {
        const int col = 16 + l15, sp = (col >> 3) ^ psw;
        Ph[prow * 32 + sp * 8 + (col & 7)] = hv;
        Pl[prow * 32 + sp * 8 + (col & 7)] = lv;
      }
    }

    // O += P V (P rows are wave-private: no barrier, lgkm ordering suffices)
    {
      const int prow = w * 16 + l15;
      const int spp = l4 ^ ((prow >> 2) & 3);
      const f16x8 pfh = *(const f16x8*)&Ph[prow * 32 + spp * 8];
      const f16x8 pfl = *(const f16x8*)&Pl[prow * 32 + spp * 8];
#pragma unroll
      for (int n = 0; n < 4; ++n) {
        const int vr = n * 16 + l15;
        const int sv = l4 ^ ((vr >> 1) & 3);
        const f16x8 vfh = *(const f16x8*)&Vh[cb][vr * 32 + sv * 8];
        const f16x8 vfl = *(const f16x8*)&Vl[cb][vr * 32 + sv * 8];
        o[n] = mfma16(pfh, vfh, o[n]);
        o[n] = mfma16(pfh, vfl, o[n]);
        o[n] = mfma16(pfl, vfh, o[n]);
      }
    }
  }

  const int mg = b * 2048 + q0 + w * 16 + l4 * 4;
#pragma unroll
  for (int r = 0; r < 4; ++r) {
    const float inv = 1.0f / lrow[r];
    const int m = mg + r;
#pragma unroll
    for (int n = 0; n < 4; ++n) {
      half_t hv, lv; split2(o[n][r] * inv, &hv, &lv);
      abh[m * 1024 + h * 64 + n * 16 + l15] = hv;
      abl[m * 1024 + h * 64 + n * 16 + l15] = lv;
    }
  }
}

// ---------------------------------------------------------------------------
extern "C" void kernel_launch(void* const* d_in, const int* in_sizes, int n_in,
                              void* d_out, int out_size, void* d_ws,
                              size_t ws_size, hipStream_t stream) {
  const float* x    = (const float*)d_in[0];
  const float* Wqre = (const float*)d_in[1];
  const float* Wqim = (const float*)d_in[2];
  const float* Wkre = (const float*)d_in[3];
  const float* Wkim = (const float*)d_in[4];
  const float* Wv   = (const float*)d_in[5];
  const float* Wo   = (const float*)d_in[6];
  const float* cosb = (const float*)d_in[7];
  const float* sinb = (const float*)d_in[8];

  char* w = (char*)d_ws;
  const size_t MB = (size_t)1 << 20;
  half_t* wh6 = (half_t*)(w + 0 * MB);    // 12 MB: 6x [1024][1024] fp16 hi
  half_t* wl6 = (half_t*)(w + 12 * MB);   // 12 MB: lo
  half_t* xh  = (half_t*)(w + 24 * MB);   // 8 MB
  half_t* xl  = (half_t*)(w + 32 * MB);   // 8 MB
  half_t* qth = (half_t*)(w + 40 * MB);   // 16 MB [4096][2048]
  half_t* qtl = (half_t*)(w + 56 * MB);   // 16 MB
  half_t* kth = (half_t*)(w + 72 * MB);   // 16 MB
  half_t* ktl = (half_t*)(w + 88 * MB);   // 16 MB
  half_t* qbh = (half_t*)(w + 104 * MB);  // 16 MB [32][2048][128]
  half_t* qbl = (half_t*)(w + 120 * MB);  // 16 MB
  half_t* kbh = (half_t*)(w + 136 * MB);  // 16 MB
  half_t* kbl = (half_t*)(w + 152 * MB);  // 16 MB
  half_t* vTh = (half_t*)(w + 168 * MB);  // 8 MB [32][64][2048]
  half_t* vTl = (half_t*)(w + 176 * MB);  // 8 MB  (total 184 MB)
  // abuf aliases qth/qtl region (qtmp fully consumed by rope before attn)
  half_t* abh = (half_t*)(w + 40 * MB);   // 8 MB [4096][1024]
  half_t* abl = (half_t*)(w + 48 * MB);   // 8 MB

  dim3 blk(256);
  convw_kernel<<<dim3(32, 32, 6), blk, 0, stream>>>(Wqre, Wqim, Wkre, Wkim, Wv,
                                                    Wo, wh6, wl6);
  convx_kernel<<<dim3(4096), blk, 0, stream>>>(x, xh, xl);
  gemm_kernel<<<dim3(8, 32, 5), blk, 0, stream>>>(xh, xl, wh6, wl6, qth, qtl,
                                                  kth, ktl, vTh, vTl, nullptr, 0);
  rope_kernel<<<dim3(16384, 2), blk, 0, stream>>>(qth, qtl, kth, ktl, cosb,
                                                  sinb, qbh, qbl, kbh, kbl);
  attn_kernel<<<dim3(16, 32), dim3(512), 0, stream>>>(qbh, qbl, kbh, kbl, vTh,
                                                      vTl, abh, abl);
  gemm_kernel<<<dim3(8, 32, 1), blk, 0, stream>>>(abh, abl, wh6, wl6, nullptr,
                                                  nullptr, nullptr, nullptr,
                                                  nullptr, nullptr,
                                                  (float*)d_out, 1);
}

// Round 6
// 513.423 us; speedup vs baseline: 1.1113x; 1.1113x over previous
//
#include <hip/hip_runtime.h>
#include <math.h>

#define SCALE_ 0.125f

typedef _Float16 half_t;
typedef __attribute__((ext_vector_type(8))) _Float16 f16x8;
typedef __attribute__((ext_vector_type(4))) _Float16 f16x4;
typedef __attribute__((ext_vector_type(4))) float f32x4;

#define AS1 __attribute__((address_space(1)))
#define AS3 __attribute__((address_space(3)))

__device__ __forceinline__ f32x4 mfma16(f16x8 a, f16x8 b, f32x4 c) {
  return __builtin_amdgcn_mfma_f32_16x16x32_f16(a, b, c, 0, 0, 0);
}
__device__ __forceinline__ void gload16(const void* g, void* l) {
  __builtin_amdgcn_global_load_lds((const AS1 void*)g, (AS3 void*)l, 16, 0, 0);
}
// split f into fp16 hi + fp16 lo (residual); hi+lo ~ 2^-22 relative accuracy
__device__ __forceinline__ void split2(float f, half_t* h, half_t* l) {
  half_t hh = (half_t)f;
  *h = hh;
  *l = (half_t)(f - (float)hh);
}

// ---------------------------------------------------------------------------
// Convert+transpose 6 weight mats: fp32 [K=1024][N=1024] -> fp16 hi/lo [N][K]
// ---------------------------------------------------------------------------
__global__ __launch_bounds__(256) void convw_kernel(
    const float* __restrict__ W0, const float* __restrict__ W1,
    const float* __restrict__ W2, const float* __restrict__ W3,
    const float* __restrict__ W4, const float* __restrict__ W5,
    half_t* __restrict__ wh, half_t* __restrict__ wl)
{
  const int z = blockIdx.z;
  const float* W = (z == 0) ? W0 : (z == 1) ? W1 : (z == 2) ? W2
                  : (z == 3) ? W3 : (z == 4) ? W4 : W5;
  half_t* outh = wh + z * 1048576;
  half_t* outl = wl + z * 1048576;
  const int n0 = blockIdx.x * 32, k0 = blockIdx.y * 32;
  const int t = threadIdx.x, r = t >> 3, c4 = (t & 7) * 4;
  __shared__ float lds[32][33];
  float4 v = *(const float4*)&W[(k0 + r) * 1024 + n0 + c4];
  lds[r][c4 + 0] = v.x; lds[r][c4 + 1] = v.y;
  lds[r][c4 + 2] = v.z; lds[r][c4 + 3] = v.w;
  __syncthreads();
  f16x4 oh, ol;
#pragma unroll
  for (int j = 0; j < 4; ++j) {
    const float f = lds[c4 + j][r];
    half_t hv, lv; split2(f, &hv, &lv);
    oh[j] = hv; ol[j] = lv;
  }
  *(f16x4*)&outh[(n0 + r) * 1024 + k0 + c4] = oh;
  *(f16x4*)&outl[(n0 + r) * 1024 + k0 + c4] = ol;
}

// ---------------------------------------------------------------------------
// x fp32 [4096][1024] -> fp16 hi/lo (same layout)
// ---------------------------------------------------------------------------
__global__ __launch_bounds__(256) void convx_kernel(
    const float* __restrict__ x, half_t* __restrict__ xh, half_t* __restrict__ xl)
{
  const int i = (blockIdx.x * 256 + threadIdx.x) * 4;
  float4 v = *(const float4*)&x[i];
  float vv[4] = {v.x, v.y, v.z, v.w};
  f16x4 oh, ol;
#pragma unroll
  for (int j = 0; j < 4; ++j) {
    half_t hv, lv; split2(vv[j], &hv, &lv);
    oh[j] = hv; ol[j] = lv;
  }
  *(f16x4*)&xh[i] = oh;
  *(f16x4*)&xl[i] = ol;
}

// ---------------------------------------------------------------------------
// Split-fp16 MFMA GEMM, m97 structure: 128x128 tile, BK=32, 4 waves (2x2),
// global_load_lds w=16, 3-term (AhBh + AhBl + AlBh).
// proj mode z: 0=Wq_re 1=Wq_im 2=Wk_re 3=Wk_im (fp16-split into qt/kt at
// remapped cols [h*128 + d (+64 for im)]), 4=Wv (written transposed split).
// final_mode: A=abuf, B=Wo (widx 5), out fp32.
// ---------------------------------------------------------------------------
__global__ __launch_bounds__(256) void gemm_kernel(
    const half_t* __restrict__ Agh, const half_t* __restrict__ Agl,
    const half_t* __restrict__ wh, const half_t* __restrict__ wl,
    half_t* __restrict__ qth, half_t* __restrict__ qtl,
    half_t* __restrict__ kth, half_t* __restrict__ ktl,
    half_t* __restrict__ vTh, half_t* __restrict__ vTl,
    float* __restrict__ outp, int final_mode)
{
  __shared__ half_t Ash[4096], Asl[4096], Bsh[4096], Bsl[4096];  // 4x8KB
  const int z = blockIdx.z;
  const int widx = final_mode ? 5 : z;
  const half_t* Bth = wh + widx * 1048576;
  const half_t* Btl = wl + widx * 1048576;

  const int n0 = blockIdx.x * 128, m0 = blockIdx.y * 128;
  const int tid = threadIdx.x, lane = tid & 63, wid = tid >> 6;
  const int wr = wid >> 1, wc = wid & 1, l15 = lane & 15, l4 = lane >> 4;

  f32x4 acc[4][4];
#pragma unroll
  for (int i = 0; i < 4; ++i)
#pragma unroll
    for (int j = 0; j < 4; ++j) acc[i][j] = (f32x4){0.f, 0.f, 0.f, 0.f};

  // staging: tile = 512 16B-slots; slot s -> row s>>2, halfcol (s&3)*8
  const int s0 = wid * 64 + lane, s1 = s0 + 256;
  const int r0 = s0 >> 2, c0 = (s0 & 3) * 8;
  const int r1 = s1 >> 2, c1 = (s1 & 3) * 8;
  half_t* Ah0 = Ash + wid * 512;        half_t* Ah1 = Ash + 2048 + wid * 512;
  half_t* Al0 = Asl + wid * 512;        half_t* Al1 = Asl + 2048 + wid * 512;
  half_t* Bh0 = Bsh + wid * 512;        half_t* Bh1 = Bsh + 2048 + wid * 512;
  half_t* Bl0 = Bsl + wid * 512;        half_t* Bl1 = Bsl + 2048 + wid * 512;

  for (int k0 = 0; k0 < 1024; k0 += 32) {
    __syncthreads();
    gload16(Agh + (m0 + r0) * 1024 + k0 + c0, Ah0);
    gload16(Agh + (m0 + r1) * 1024 + k0 + c1, Ah1);
    gload16(Agl + (m0 + r0) * 1024 + k0 + c0, Al0);
    gload16(Agl + (m0 + r1) * 1024 + k0 + c1, Al1);
    gload16(Bth + (n0 + r0) * 1024 + k0 + c0, Bh0);
    gload16(Bth + (n0 + r1) * 1024 + k0 + c1, Bh1);
    gload16(Btl + (n0 + r0) * 1024 + k0 + c0, Bl0);
    gload16(Btl + (n0 + r1) * 1024 + k0 + c1, Bl1);
    __syncthreads();
    f16x8 ah[4], al[4], bh[4], bl[4];
#pragma unroll
    for (int i = 0; i < 4; ++i) {
      const int ro = (wr * 64 + i * 16 + l15) * 32 + l4 * 8;
      ah[i] = *(const f16x8*)&Ash[ro];
      al[i] = *(const f16x8*)&Asl[ro];
    }
#pragma unroll
    for (int j = 0; j < 4; ++j) {
      const int ro = (wc * 64 + j * 16 + l15) * 32 + l4 * 8;
      bh[j] = *(const f16x8*)&Bsh[ro];
      bl[j] = *(const f16x8*)&Bsl[ro];
    }
#pragma unroll
    for (int i = 0; i < 4; ++i)
#pragma unroll
      for (int j = 0; j < 4; ++j) {
        acc[i][j] = mfma16(ah[i], bh[j], acc[i][j]);
        acc[i][j] = mfma16(ah[i], bl[j], acc[i][j]);
        acc[i][j] = mfma16(al[i], bh[j], acc[i][j]);
      }
  }

#pragma unroll
  for (int i = 0; i < 4; ++i) {
    const int mb = m0 + wr * 64 + i * 16 + l4 * 4;
#pragma unroll
    for (int j = 0; j < 4; ++j) {
      const int n = n0 + wc * 64 + j * 16 + l15;
      if (final_mode) {
#pragma unroll
        for (int r = 0; r < 4; ++r) outp[(mb + r) * 1024 + n] = acc[i][j][r];
      } else if (z < 4) {
        half_t* dh = (z < 2) ? qth : kth;
        half_t* dl = (z < 2) ? qtl : ktl;
        const int colr = (n >> 6) * 128 + (n & 63) + ((z & 1) ? 64 : 0);
#pragma unroll
        for (int r = 0; r < 4; ++r) {
          half_t hv, lv; split2(acc[i][j][r], &hv, &lv);
          dh[(mb + r) * 2048 + colr] = hv;
          dl[(mb + r) * 2048 + colr] = lv;
        }
      } else {  // V: write transposed split, [bh][d][t], r -> contiguous t
        const int hh = n >> 6, d = n & 63;
        const int bq = mb >> 11, t = mb & 2047;
        f16x4 vh4, vl4;
#pragma unroll
        for (int r = 0; r < 4; ++r) {
          half_t hv, lv; split2(acc[i][j][r], &hv, &lv);
          vh4[r] = hv; vl4[r] = lv;
        }
        const int off = ((bq * 16 + hh) * 64 + d) * 2048 + t;
        *(f16x4*)&vTh[off] = vh4;
        *(f16x4*)&vTl[off] = vl4;
      }
    }
  }
}

// ---------------------------------------------------------------------------
// RoPE: reconstruct fp32 from hi+lo, rotate, re-split to qb/kb [bh][t][128]
// (re|im), q pre-scaled by SCALE. One 64-lane wave per (m,h).
// ---------------------------------------------------------------------------
__global__ __launch_bounds__(256) void rope_kernel(
    const half_t* __restrict__ qth, const half_t* __restrict__ qtl,
    const half_t* __restrict__ kth, const half_t* __restrict__ ktl,
    const float* __restrict__ cosb, const float* __restrict__ sinb,
    half_t* __restrict__ qbh, half_t* __restrict__ qbl,
    half_t* __restrict__ kbh, half_t* __restrict__ kbl)
{
  const int z = blockIdx.y;
  const int g = blockIdx.x * 4 + (threadIdx.x >> 6);
  const int d = threadIdx.x & 63;
  const int m = g >> 4, h = g & 15;
  const int b = m >> 11, t = m & 2047;
  const half_t* sh = (z ? kth : qth) + m * 2048 + h * 128;
  const half_t* sl = (z ? ktl : qtl) + m * 2048 + h * 128;
  const float re = (float)sh[d] + (float)sl[d];
  const float im = (float)sh[64 + d] + (float)sl[64 + d];
  const float c = cosb[t * 64 + d], s = sinb[t * 64 + d];
  float rer = re * c - im * s;
  float imr = re * s + im * c;
  if (z == 0) { rer *= SCALE_; imr *= SCALE_; }
  half_t* dh = (z ? kbh : qbh) + ((b * 16 + h) * 2048 + t) * 128;
  half_t* dl = (z ? kbl : qbl) + ((b * 16 + h) * 2048 + t) * 128;
  half_t hv, lv;
  split2(rer, &hv, &lv); dh[d] = hv;      dl[d] = lv;
  split2(imr, &hv, &lv); dh[64 + d] = hv; dl[64 + d] = lv;
}

// ---------------------------------------------------------------------------
// Flash attention, split-fp16 MFMA. 512 thr (8 waves); wave w owns q-rows
// q0+w*16..+15. QB=128, KB=32, D'=128, Dv=64.
// Flat 512-block grid with balance+locality mapping:
//   bh = i&31 (=> i==bh mod 8: all 16 qt-blocks of a bh share an XCD/L2);
//   qt = i<256 ? 15-idx : idx, idx=(i>>5)&7  (=> blocks i and i+256 have
//   qt sums of 15: every CU pair does exactly 68 tile-iterations).
// Single barrier per k-tile; double-buffered K/V via global_load_lds with
// pre-swizzled global source; P LDS is wave-private.
// ---------------------------------------------------------------------------
__global__ __launch_bounds__(512) void attn_kernel(
    const half_t* __restrict__ qbh, const half_t* __restrict__ qbl,
    const half_t* __restrict__ kbh, const half_t* __restrict__ kbl,
    const half_t* __restrict__ vTh, const half_t* __restrict__ vTl,
    half_t* __restrict__ abh, half_t* __restrict__ abl)
{
  const int i = blockIdx.x;                 // 0..511
  const int bh = i & 31;
  const int idx = (i >> 5) & 7;
  const int qt = (i < 256) ? (15 - idx) : idx;
  const int b = bh >> 4, h = bh & 15;
  const int tid = threadIdx.x, lane = tid & 63, w = tid >> 6;
  const int l15 = lane & 15, l4 = lane >> 4;
  const int q0 = qt * 128;

  __shared__ half_t Kh[2][4096], Kl[2][4096];  // [32 t][128 d] per buf
  __shared__ half_t Vh[2][2048], Vl[2][2048];  // [64 d][32 t] per buf
  __shared__ half_t Ph[4096], Pl[4096];        // [128 q][32 k]

  // Q fragments (hi/lo), rows q0 + w*16 + l15
  f16x8 qh[4], ql[4];
  {
    const int qoff = (bh * 2048 + q0 + w * 16 + l15) * 128;
#pragma unroll
    for (int c = 0; c < 4; ++c) {
      qh[c] = *(const f16x8*)(qbh + qoff + c * 32 + l4 * 8);
      ql[c] = *(const f16x8*)(qbl + qoff + c * 32 + l4 * 8);
    }
  }

  f32x4 o[4];
#pragma unroll
  for (int n = 0; n < 4; ++n) o[n] = (f32x4){0.f, 0.f, 0.f, 0.f};
  float mrow[4] = {-3e38f, -3e38f, -3e38f, -3e38f};
  float lrow[4] = {0.f, 0.f, 0.f, 0.f};

  const half_t* kh_p = kbh + (size_t)bh * 2048 * 128;
  const half_t* kl_p = kbl + (size_t)bh * 2048 * 128;
  const half_t* vh_p = vTh + (size_t)bh * 64 * 2048;
  const half_t* vl_p = vTl + (size_t)bh * 64 * 2048;

  // staging geometry: K tile = 512 16B-slots (wave w -> slots w*64+lane);
  // lane's LDS slot is linear (gload_lds scatters lane*16B); the global
  // source is pre-swizzled so that swizzled READS see the right data.
  const int krow = w * 4 + (lane >> 4);            // 0..31
  const int ks = lane & 15;
  const int kg = (ks & 8) | ((ks & 7) ^ (krow & 7));  // involution
  const int vrow = (w & 3) * 16 + (lane >> 2);     // 0..63
  const int vs = lane & 3;
  const int vg = vs ^ ((vrow >> 1) & 3);           // involution
  const bool vhi = (w < 4);

  const int nkt = 4 * (qt + 1);
  const int qminw = q0 + w * 16, qmaxw = qminw + 15;

  // prologue: stage tile 0 into buf 0
  gload16(kh_p + (krow) * 128 + kg * 8, &Kh[0][w * 512]);
  gload16(kl_p + (krow) * 128 + kg * 8, &Kl[0][w * 512]);
  if (vhi) gload16(vh_p + vrow * 2048 + vg * 8, &Vh[0][(w & 3) * 512]);
  else     gload16(vl_p + vrow * 2048 + vg * 8, &Vl[0][(w & 3) * 512]);

  for (int kt = 0; kt < nkt; ++kt) {
    const int k0 = kt * 32;
    const int cb = kt & 1;
    __syncthreads();  // drains tile-kt loads; all waves done reading buf cb^1

    // prefetch tile kt+1 (clamped) into the other buffer; lands during compute
    {
      const int k0n = (kt + 1 < nkt) ? k0 + 32 : 0;
      const int nb = cb ^ 1;
      gload16(kh_p + (k0n + krow) * 128 + kg * 8, &Kh[nb][w * 512]);
      gload16(kl_p + (k0n + krow) * 128 + kg * 8, &Kl[nb][w * 512]);
      if (vhi) gload16(vh_p + vrow * 2048 + k0n + vg * 8, &Vh[nb][(w & 3) * 512]);
      else     gload16(vl_p + vrow * 2048 + k0n + vg * 8, &Vl[nb][(w & 3) * 512]);
    }

    if (k0 > qmaxw) continue;  // fully masked for this wave (barrier stays aligned)

    // S = Q K^T (k-cols k0 + n*16+l15, n=0..1), 3-term split
    f32x4 s[2];
    s[0] = (f32x4){0.f, 0.f, 0.f, 0.f};
    s[1] = (f32x4){0.f, 0.f, 0.f, 0.f};
#pragma unroll
    for (int c = 0; c < 4; ++c) {
#pragma unroll
      for (int n = 0; n < 2; ++n) {
        const int row = n * 16 + l15;
        const int co = c * 4 + l4;
        const int sr = (co & 8) | ((co & 7) ^ (row & 7));
        const f16x8 kfh = *(const f16x8*)&Kh[cb][row * 128 + sr * 8];
        const f16x8 kfl = *(const f16x8*)&Kl[cb][row * 128 + sr * 8];
        s[n] = mfma16(qh[c], kfh, s[n]);
        s[n] = mfma16(qh[c], kfl, s[n]);
        s[n] = mfma16(ql[c], kfh, s[n]);
      }
    }

    if (k0 + 31 > qminw) {  // partial tile: elementwise causal mask (global idx)
#pragma unroll
      for (int n = 0; n < 2; ++n)
#pragma unroll
        for (int r = 0; r < 4; ++r)
          if (k0 + n * 16 + l15 > qminw + l4 * 4 + r) s[n][r] = -3e38f;
    }

    // online softmax (row groups = 16 contiguous lanes)
#pragma unroll
    for (int r = 0; r < 4; ++r) {
      float mx = fmaxf(s[0][r], s[1][r]);
      mx = fmaxf(mx, __shfl_xor(mx, 1));
      mx = fmaxf(mx, __shfl_xor(mx, 2));
      mx = fmaxf(mx, __shfl_xor(mx, 4));
      mx = fmaxf(mx, __shfl_xor(mx, 8));
      const float mnew = fmaxf(mrow[r], mx);
      const float alpha = __expf(mrow[r] - mnew);
      const float p0 = __expf(s[0][r] - mnew);
      const float p1 = __expf(s[1][r] - mnew);
      float rs = p0 + p1;
      rs += __shfl_xor(rs, 1);
      rs += __shfl_xor(rs, 2);
      rs += __shfl_xor(rs, 4);
      rs += __shfl_xor(rs, 8);
      lrow[r] = lrow[r] * alpha + rs;
      mrow[r] = mnew;
#pragma unroll
      for (int n = 0; n < 4; ++n) o[n][r] *= alpha;
      const int prow = w * 16 + l4 * 4 + r;
      const int psw = (prow >> 2) & 3;
      half_t hv, lv;
      split2(p0, &hv, &lv);
      {
        const int col = l15, sp = (col >> 3) ^ psw;
        Ph[prow * 32 + sp * 8 + (col & 7)] = hv;
        Pl[prow * 32 + sp * 8 + (col & 7)] = lv;
      }
      split2(p1, &hv, &lv);
      {
        const int col = 16 + l15, sp = (col >> 3) ^ psw;
        Ph[prow * 32 + sp * 8 + (col & 7)] = hv;
        Pl[prow * 32 + sp * 8 + (col & 7)] = lv;
      }
    }

    // O += P V (P rows are wave-private: no barrier, lgkm ordering suffices)
    {
      const int prow = w * 16 + l15;
      const int spp = l4 ^ ((prow >> 2) & 3);
      const f16x8 pfh = *(const f16x8*)&Ph[prow * 32 + spp * 8];
      const f16x8 pfl = *(const f16x8*)&Pl[prow * 32 + spp * 8];
#pragma unroll
      for (int n = 0; n < 4; ++n) {
        const int vr = n * 16 + l15;
        const int sv = l4 ^ ((vr >> 1) & 3);
        const f16x8 vfh = *(const f16x8*)&Vh[cb][vr * 32 + sv * 8];
        const f16x8 vfl = *(const f16x8*)&Vl[cb][vr * 32 + sv * 8];
        o[n] = mfma16(pfh, vfh, o[n]);
        o[n] = mfma16(pfh, vfl, o[n]);
        o[n] = mfma16(pfl, vfh, o[n]);
      }
    }
  }

  const int mg = b * 2048 + q0 + w * 16 + l4 * 4;
#pragma unroll
  for (int r = 0; r < 4; ++r) {
    const float inv = 1.0f / lrow[r];
    const int m = mg + r;
#pragma unroll
    for (int n = 0; n < 4; ++n) {
      half_t hv, lv; split2(o[n][r] * inv, &hv, &lv);
      abh[m * 1024 + h * 64 + n * 16 + l15] = hv;
      abl[m * 1024 + h * 64 + n * 16 + l15] = lv;
    }
  }
}

// ---------------------------------------------------------------------------
extern "C" void kernel_launch(void* const* d_in, const int* in_sizes, int n_in,
                              void* d_out, int out_size, void* d_ws,
                              size_t ws_size, hipStream_t stream) {
  const float* x    = (const float*)d_in[0];
  const float* Wqre = (const float*)d_in[1];
  const float* Wqim = (const float*)d_in[2];
  const float* Wkre = (const float*)d_in[3];
  const float* Wkim = (const float*)d_in[4];
  const float* Wv   = (const float*)d_in[5];
  const float* Wo   = (const float*)d_in[6];
  const float* cosb = (const float*)d_in[7];
  const float* sinb = (const float*)d_in[8];

  char* w = (char*)d_ws;
  const size_t MB = (size_t)1 << 20;
  half_t* wh6 = (half_t*)(w + 0 * MB);    // 12 MB: 6x [1024][1024] fp16 hi
  half_t* wl6 = (half_t*)(w + 12 * MB);   // 12 MB: lo
  half_t* xh  = (half_t*)(w + 24 * MB);   // 8 MB
  half_t* xl  = (half_t*)(w + 32 * MB);   // 8 MB
  half_t* qth = (half_t*)(w + 40 * MB);   // 16 MB [4096][2048]
  half_t* qtl = (half_t*)(w + 56 * MB);   // 16 MB
  half_t* kth = (half_t*)(w + 72 * MB);   // 16 MB
  half_t* ktl = (half_t*)(w + 88 * MB);   // 16 MB
  half_t* qbh = (half_t*)(w + 104 * MB);  // 16 MB [32][2048][128]
  half_t* qbl = (half_t*)(w + 120 * MB);  // 16 MB
  half_t* kbh = (half_t*)(w + 136 * MB);  // 16 MB
  half_t* kbl = (half_t*)(w + 152 * MB);  // 16 MB
  half_t* vTh = (half_t*)(w + 168 * MB);  // 8 MB [32][64][2048]
  half_t* vTl = (half_t*)(w + 176 * MB);  // 8 MB  (total 184 MB)
  // abuf aliases qth/qtl region (qtmp fully consumed by rope before attn)
  half_t* abh = (half_t*)(w + 40 * MB);   // 8 MB [4096][1024]
  half_t* abl = (half_t*)(w + 48 * MB);   // 8 MB

  dim3 blk(256);
  convw_kernel<<<dim3(32, 32, 6), blk, 0, stream>>>(Wqre, Wqim, Wkre, Wkim, Wv,
                                                    Wo, wh6, wl6);
  convx_kernel<<<dim3(4096), blk, 0, stream>>>(x, xh, xl);
  gemm_kernel<<<dim3(8, 32, 5), blk, 0, stream>>>(xh, xl, wh6, wl6, qth, qtl,
                                                  kth, ktl, vTh, vTl, nullptr, 0);
  rope_kernel<<<dim3(16384, 2), blk, 0, stream>>>(qth, qtl, kth, ktl, cosb,
                                                  sinb, qbh, qbl, kbh, kbl);
  attn_kernel<<<dim3(512), dim3(512), 0, stream>>>(qbh, qbl, kbh, kbl, vTh,
                                                   vTl, abh, abl);
  gemm_kernel<<<dim3(8, 32, 1), blk, 0, stream>>>(abh, abl, wh6, wl6, nullptr,
                                                  nullptr, nullptr, nullptr,
                                                  nullptr, nullptr,
                                                  (float*)d_out, 1);
}